// Round 2
// baseline (193.392 us; speedup 1.0000x reference)
//
#include <hip/hip_runtime.h>
#include <hip/hip_bf16.h>

#define B_   2
#define N_   2048
#define DM_  1024
#define H_   16
#define DK_  64
#define BLK_ 128
#define TB_  16

typedef unsigned short u16;
typedef unsigned int   u32;
using bf16x8 = __attribute__((ext_vector_type(8))) __bf16;
using f32x4  = __attribute__((ext_vector_type(4))) float;

#define KPAD 72    // Ks rows of 64 bf16 (+8): min-phase on frag reads & stores
#define VPAD 136   // Vts rows of 128 bf16 (+8)
#define PPAD 136   // Ps rows of 128 bf16 (+8): b64 writes 2-way (free), b128 reads min-phase
#define OPAD 68    // Os rows of 64 fp32 (+4)

__device__ __forceinline__ u32 pack_bf16(float a, float b) {
  __hip_bfloat162 h = __float22bfloat162_rn(make_float2(a, b));
  u32 u; __builtin_memcpy(&u, &h, 4); return u;
}
__device__ __forceinline__ bf16x8 pack8(float4 f0, float4 f1, float sc) {
  u32 w[4];
  w[0] = pack_bf16(f0.x * sc, f0.y * sc); w[1] = pack_bf16(f0.z * sc, f0.w * sc);
  w[2] = pack_bf16(f1.x * sc, f1.y * sc); w[3] = pack_bf16(f1.z * sc, f1.w * sc);
  bf16x8 r; __builtin_memcpy(&r, w, 16); return r;
}

// ---------------- pre-pass 1: K -> (b,h,n,d) bf16 ; V -> (b,h,d,n) bf16 ----------------
__global__ void kv_convert(const float* __restrict__ k, const float* __restrict__ v,
                           u16* __restrict__ kb, u16* __restrict__ vt) {
  __shared__ u16 tile[BLK_][DK_ + 2];
  const int b = blockIdx.z, h = blockIdx.y, nb = blockIdx.x;
  const int t = threadIdx.x;
  const int rr = t >> 4, cc = (t & 15) * 4;
  // K: straight convert, (n,d) layout
  {
    const float* kg = k + ((size_t)(b * N_ + nb * BLK_)) * DM_ + h * DK_;
    u16* kd = kb + ((size_t)((b * H_ + h) * N_) + nb * BLK_) * DK_;
#pragma unroll
    for (int i = 0; i < 8; ++i) {
      const int r = rr + i * 16;
      const float4 f = *(const float4*)(kg + (size_t)r * DM_ + cc);
      *(uint2*)(kd + r * DK_ + cc) = make_uint2(pack_bf16(f.x, f.y), pack_bf16(f.z, f.w));
    }
  }
  // V: transpose via LDS, (d,n) layout
  {
    const float* vg = v + ((size_t)(b * N_ + nb * BLK_)) * DM_ + h * DK_;
#pragma unroll
    for (int i = 0; i < 8; ++i) {
      const int r = rr + i * 16;
      const float4 f = *(const float4*)(vg + (size_t)r * DM_ + cc);
      *(u32*)(&tile[r][cc])     = pack_bf16(f.x, f.y);
      *(u32*)(&tile[r][cc + 2]) = pack_bf16(f.z, f.w);
    }
    __syncthreads();
    // d = t&63: a wave reads 64 distinct d (32 distinct dword banks, pairs share a
    // dword -> broadcast) instead of d=t>>2 whose rows landed on 8 banks.
    const int d = t & 63, n0 = (t >> 6) * 32;
    u16* og = vt + ((size_t)(b * H_ + h) * DK_ + d) * N_ + nb * BLK_ + n0;
#pragma unroll
    for (int j = 0; j < 32; j += 8) {
      u16 tmp[8];
#pragma unroll
      for (int x = 0; x < 8; ++x) tmp[x] = tile[n0 + j + x][d];
      uint4 w; __builtin_memcpy(&w, tmp, 16);
      *(uint4*)(og + j) = w;
    }
  }
}

// ---------------- pre-pass 2: mask + block_sparse -> flags {0,1,2} ----------------
__global__ void mask_flags_kernel(const int* __restrict__ mask, const int* __restrict__ bs,
                                  int* __restrict__ flags) {
  const int blk = blockIdx.x;
  const int kb = blk % TB_, qb = (blk / TB_) % TB_, b = blk / (TB_ * TB_);
  const int t = threadIdx.x;
  const int* mg = mask + (size_t)b * N_ * N_ + (size_t)(qb * BLK_) * N_ + kb * BLK_;
  int all1 = 1, any1 = 0;
  for (int i = t; i < BLK_ * BLK_ / 4; i += 256) {
    const int r = i >> 5, c = (i & 31) * 4;
    const int4 mv = *(const int4*)(mg + (size_t)r * N_ + c);
    all1 &= (mv.x != 0) & (mv.y != 0) & (mv.z != 0) & (mv.w != 0);
    any1 |= (mv.x != 0) | (mv.y != 0) | (mv.z != 0) | (mv.w != 0);
  }
  __shared__ int sAll[4], sAny[4];
  const int wv = t >> 6;
  const int wAll = __all(all1), wAny = __any(any1);
  if ((t & 63) == 0) { sAll[wv] = wAll; sAny[wv] = wAny; }
  __syncthreads();
  if (t == 0) {
    const int A = sAll[0] & sAll[1] & sAll[2] & sAll[3];
    const int O = sAny[0] | sAny[1] | sAny[2] | sAny[3];
    int f = 0;
    if (bs[qb * TB_ + kb] != 0 && O) f = A ? 1 : 2;
    flags[blk] = f;
  }
}

// straight-line prefetch (NO lambda: reference-captured arrays defeated SROA in R4
// -> kr/vr went to scratch -> +94MB WRITE_SIZE, the known spill regression)
#define ISSUE_KV(blk_) do {                                                     \
    const u16* ks_ = kbase + (size_t)(blk_) * BLK_ * DK_;                       \
    const u16* vs_ = vbase + (blk_) * BLK_;                                     \
    _Pragma("unroll")                                                           \
    for (int j_ = 0; j_ < 4; ++j_) {                                            \
      const int i_ = t + 256 * j_;                                              \
      kr[j_] = *(const uint4*)(ks_ + i_ * 8);                                   \
      vr[j_] = *(const uint4*)(vs_ + (size_t)(i_ >> 4) * N_ + (i_ & 15) * 8);   \
    }                                                                           \
  } while (0)

// ---------------- main: block-sparse flash attention ----------------
// WG = 128 q rows. Grid 512 = (bh&31) + 32*qb -> same-(b,h) WGs share XCD.
// LDS (70656 B) caps residency at 2 WG/CU = 2 waves/SIMD. T14 prefetch: next
// block's K/V global loads are issued right after the staging barrier and sit in
// registers until the NEXT iteration's ds_write -- the L2/HBM latency that used to
// sit fully exposed between the two barriers (all 8 waves of the CU stalled on the
// same vmcnt drain) now hides under QK+softmax+PV. Sequential per-nt QK (st[8]
// reused) keeps live VGPRs well under the 2-wave/SIMD cap of 256 -- no spills.
__global__ __launch_bounds__(256, 2)
void attn_kernel(const float* __restrict__ q_, const u16* __restrict__ kb_,
                 const u16* __restrict__ vt, const float* __restrict__ tau_p,
                 const int* __restrict__ mask, const int* __restrict__ flags,
                 float* __restrict__ o_out, float* __restrict__ l_out,
                 float* __restrict__ m_out) {
  __shared__ __align__(16) u16 lds[BLK_ * KPAD + DK_ * VPAD + BLK_ * PPAD];  // 70656 B
  u16* Ks  = lds;                       // 128 x KPAD
  u16* Vts = Ks + BLK_ * KPAD;          // 64 x VPAD
  u16* Ps  = Vts + DK_ * VPAD;          // 128 x PPAD (wave-private rows)
  float* Os = (float*)lds;              // 128 x OPAD fp32 epilogue overlay (34816 <= 35840)

  const int idx = blockIdx.x;
  const int bh = idx & 31, qb128 = idx >> 5;
  const int b = bh >> 4, h = bh & 15;
  const int t = threadIdx.x;
  const int wave = t >> 6, lane = t & 63, quad = lane >> 4, col = lane & 15;

  // active-kb bitmasks (uniform)
  const int* flg = flags + (b * TB_ + qb128) * TB_;
  u32 actmask = 0, mixmask = 0;
#pragma unroll
  for (int i = 0; i < TB_; ++i) {
    const int f = flg[i];
    actmask |= (f != 0) ? (1u << i) : 0u;
    mixmask |= (f == 2) ? (1u << i) : 0u;
  }

  const u16* kbase = kb_ + (size_t)(b * H_ + h) * N_ * DK_;
  const u16* vbase = vt + (size_t)(b * H_ + h) * DK_ * N_;

  uint4 kr[4], vr[4];
  u32 rem = actmask;
  int cur = -1;
  if (rem) { cur = (int)__builtin_ctz(rem); rem &= rem - 1; ISSUE_KV(cur); }  // flies under Q pack

  int qg[2];
  qg[0] = qb128 * BLK_ + wave * 32 + col;
  qg[1] = qg[0] + 16;

  // Q B-fragments straight from fp32 global (one-time; scale + log2e folded)
  const float qscale = tau_p[0] * 0.125f * 1.44269504f;
  bf16x8 bq[2][2];
#pragma unroll
  for (int nt = 0; nt < 2; ++nt) {
    const float* qr = q_ + ((size_t)(b * N_ + qg[nt])) * DM_ + h * DK_;
#pragma unroll
    for (int half = 0; half < 2; ++half) {
      const float4 f0 = *(const float4*)(qr + half * 32 + quad * 8);
      const float4 f1 = *(const float4*)(qr + half * 32 + quad * 8 + 4);
      bq[nt][half] = pack8(f0, f1, qscale);
    }
  }

  float m_run[2]  = {-INFINITY, -INFINITY};   // softmax base (may lag true max by <= THR)
  float m_true[2] = {-INFINITY, -INFINITY};   // true running max (for m_out / l_out fixup)
  float l_run[2] = {0.f, 0.f};
  f32x4 oacc[2][4];
#pragma unroll
  for (int nt = 0; nt < 2; ++nt)
#pragma unroll
    for (int mt = 0; mt < 4; ++mt) oacc[nt][mt] = (f32x4){0.f, 0.f, 0.f, 0.f};

  while (cur >= 0) {
    const int mix = (mixmask >> cur) & 1;

    __syncthreads();  // previous iter's K/V fragment reads complete
    // ---- write prefetched K,V regs -> LDS (loads have been in flight all iter) ----
#pragma unroll
    for (int j = 0; j < 4; ++j) {
      const int i = t + 256 * j;
      *(uint4*)(Ks + (i >> 3) * KPAD + (i & 7) * 8) = kr[j];
      *(uint4*)(Vts + (i >> 4) * VPAD + (i & 15) * 8) = vr[j];
    }
    __syncthreads();  // staging visible

    // ---- T14: issue next block's loads now; WAR on kr/vr resolves at ds_write issue ----
    int nxt = -1;
    if (rem) { nxt = (int)__builtin_ctz(rem); rem &= rem - 1; ISSUE_KV(nxt); }

    // ---- per q-tile: S^T = K.Q^T, softmax, P -> wave-private LDS ----
#pragma unroll
    for (int nt = 0; nt < 2; ++nt) {
      f32x4 st[8];
      __builtin_amdgcn_s_setprio(1);
#pragma unroll
      for (int kt = 0; kt < 8; ++kt) {
        const bf16x8 a0 = *(const bf16x8*)(Ks + (kt * 16 + col) * KPAD + quad * 8);
        const bf16x8 a1 = *(const bf16x8*)(Ks + (kt * 16 + col) * KPAD + 32 + quad * 8);
        f32x4 c = (f32x4){0.f, 0.f, 0.f, 0.f};
        c = __builtin_amdgcn_mfma_f32_16x16x32_bf16(a0, bq[nt][0], c, 0, 0, 0);
        c = __builtin_amdgcn_mfma_f32_16x16x32_bf16(a1, bq[nt][1], c, 0, 0, 0);
        st[kt] = c;
      }
      __builtin_amdgcn_s_setprio(0);
      if (mix) {  // token mask (not taken with all-ones mask)
        const int* mg = mask + (size_t)b * N_ * N_ + (size_t)qg[nt] * N_ + cur * BLK_;
#pragma unroll
        for (int kt = 0; kt < 8; ++kt) {
          const int4 mv = *(const int4*)(mg + kt * 16 + quad * 4);
          if (!mv.x) st[kt][0] = -1e30f;
          if (!mv.y) st[kt][1] = -1e30f;
          if (!mv.z) st[kt][2] = -1e30f;
          if (!mv.w) st[kt][3] = -1e30f;
        }
      }
      float mx = -INFINITY;
#pragma unroll
      for (int kt = 0; kt < 8; ++kt)
        mx = fmaxf(mx, fmaxf(fmaxf(st[kt][0], st[kt][1]), fmaxf(st[kt][2], st[kt][3])));
      mx = fmaxf(mx, __shfl_xor(mx, 16, 64));
      mx = fmaxf(mx, __shfl_xor(mx, 32, 64));
      m_true[nt] = fmaxf(m_true[nt], mx);

      // T13 defer-rescale: skip the O/l rescale unless a row grew past THR=8 (log2).
      const float mold = m_run[nt];
      float mnew = mold;
      if (!__all(mx <= mold + 8.f)) {
        mnew = fmaxf(mold, mx);
        const float alpha = __builtin_amdgcn_exp2f(mold - mnew);
        l_run[nt] *= alpha;
#pragma unroll
        for (int mt = 0; mt < 4; ++mt)
#pragma unroll
          for (int r = 0; r < 4; ++r) oacc[nt][mt][r] *= alpha;
        m_run[nt] = mnew;
      }

      const int qloc = wave * 32 + nt * 16 + col;
      float s = 0.f;
      if (!mix) {
#pragma unroll
        for (int kt = 0; kt < 8; ++kt) {
          const float p0 = __builtin_amdgcn_exp2f(st[kt][0] - mnew);
          const float p1 = __builtin_amdgcn_exp2f(st[kt][1] - mnew);
          const float p2 = __builtin_amdgcn_exp2f(st[kt][2] - mnew);
          const float p3 = __builtin_amdgcn_exp2f(st[kt][3] - mnew);
          s += (p0 + p1) + (p2 + p3);
          *(uint2*)(Ps + qloc * PPAD + kt * 16 + quad * 4) =
              make_uint2(pack_bf16(p0, p1), pack_bf16(p2, p3));
        }
      } else {
#pragma unroll
        for (int kt = 0; kt < 8; ++kt) {
          const float p0 = st[kt][0] <= -1e29f ? 0.f : __builtin_amdgcn_exp2f(st[kt][0] - mnew);
          const float p1 = st[kt][1] <= -1e29f ? 0.f : __builtin_amdgcn_exp2f(st[kt][1] - mnew);
          const float p2 = st[kt][2] <= -1e29f ? 0.f : __builtin_amdgcn_exp2f(st[kt][2] - mnew);
          const float p3 = st[kt][3] <= -1e29f ? 0.f : __builtin_amdgcn_exp2f(st[kt][3] - mnew);
          s += (p0 + p1) + (p2 + p3);
          *(uint2*)(Ps + qloc * PPAD + kt * 16 + quad * 4) =
              make_uint2(pack_bf16(p0, p1), pack_bf16(p2, p3));
        }
      }
      s += __shfl_xor(s, 16, 64);
      s += __shfl_xor(s, 32, 64);
      l_run[nt] += s;
    }

    // ---- O^T += V^T . P^T ; P fragments from wave-private LDS (no barrier) ----
    __builtin_amdgcn_s_setprio(1);
#pragma unroll
    for (int ks = 0; ks < 4; ++ks) {
      bf16x8 bfrag[2];
#pragma unroll
      for (int nt = 0; nt < 2; ++nt)
        bfrag[nt] = *(const bf16x8*)(Ps + (wave * 32 + nt * 16 + col) * PPAD + ks * 32 + quad * 8);
#pragma unroll
      for (int mt = 0; mt < 4; ++mt) {
        const bf16x8 av = *(const bf16x8*)(Vts + (mt * 16 + col) * VPAD + ks * 32 + quad * 8);
#pragma unroll
        for (int nt = 0; nt < 2; ++nt)
          oacc[nt][mt] = __builtin_amdgcn_mfma_f32_16x16x32_bf16(av, bfrag[nt], oacc[nt][mt], 0, 0, 0);
      }
    }
    __builtin_amdgcn_s_setprio(0);
    cur = nxt;
  }

  // ---- epilogue: normalize, transpose O through LDS overlay, coalesced writes ----
  __syncthreads();  // all waves done with Ks/Vts before Os overlay
#pragma unroll
  for (int nt = 0; nt < 2; ++nt) {
    const float inv = l_run[nt] > 0.f ? 1.f / l_run[nt] : 1.f;
    const int qloc = wave * 32 + nt * 16 + col;
#pragma unroll
    for (int mt = 0; mt < 4; ++mt) {
      float4 w = make_float4(oacc[nt][mt][0] * inv, oacc[nt][mt][1] * inv,
                             oacc[nt][mt][2] * inv, oacc[nt][mt][3] * inv);
      *(float4*)(Os + qloc * OPAD + mt * 16 + quad * 4) = w;
    }
  }
  __syncthreads();
  float* ob = o_out + ((size_t)(b * N_ + qb128 * BLK_)) * DM_ + h * DK_;
#pragma unroll
  for (int j = 0; j < 8; ++j) {
    const int i = t + 256 * j;
    const int r = i >> 4, c4 = (i & 15) * 4;
    const float4 w = *(const float4*)(Os + r * OPAD + c4);
    *(float4*)(ob + (size_t)r * DM_ + c4) = w;
  }
  if (quad == 0) {
#pragma unroll
    for (int nt = 0; nt < 2; ++nt) {
      const size_t oi = (size_t)(b * H_ + h) * N_ + qg[nt];
      // l_run is consistent with base m_run; convert to the true-max base.
      const float lv = l_run[nt] > 0.f
          ? l_run[nt] * __builtin_amdgcn_exp2f(m_run[nt] - m_true[nt]) : 0.f;
      l_out[oi] = lv;
      m_out[oi] = l_run[nt] > 0.f ? m_true[nt] * 0.69314718056f : -INFINITY;
    }
  }
}

extern "C" void kernel_launch(void* const* d_in, const int* in_sizes, int n_in,
                              void* d_out, int out_size, void* d_ws, size_t ws_size,
                              hipStream_t stream) {
  const float* q   = (const float*)d_in[0];
  const float* k   = (const float*)d_in[1];
  const float* v   = (const float*)d_in[2];
  const float* tau = (const float*)d_in[3];
  const int* mask  = (const int*)d_in[4];
  const int* bs    = (const int*)d_in[5];
  float* out = (float*)d_out;

  const size_t plane = (size_t)B_ * H_ * N_ * DK_;
  u16* kb = (u16*)d_ws;
  u16* vt = kb + plane;
  int* flags = (int*)(vt + plane);

  kv_convert<<<dim3(N_ / BLK_, H_, B_), 256, 0, stream>>>(k, v, kb, vt);
  mask_flags_kernel<<<B_ * TB_ * TB_, 256, 0, stream>>>(mask, bs, flags);

  float* o_out = out;
  float* l_out = out + (size_t)B_ * N_ * DM_;
  float* m_out = l_out + (size_t)B_ * H_ * N_;
  attn_kernel<<<dim3(TB_ * 32), 256, 0, stream>>>(q, kb, vt, tau, mask, flags,
                                                  o_out, l_out, m_out);
}

// Round 3
// 192.113 us; speedup vs baseline: 1.0067x; 1.0067x over previous
//
#include <hip/hip_runtime.h>
#include <hip/hip_bf16.h>

#define B_   2
#define N_   2048
#define DM_  1024
#define H_   16
#define DK_  64
#define BLK_ 128
#define TB_  16

typedef unsigned short u16;
typedef unsigned int   u32;
using bf16x8 = __attribute__((ext_vector_type(8))) __bf16;
using f32x4  = __attribute__((ext_vector_type(4))) float;

#define KPAD 72    // Ks rows of 64 bf16 (+8): min-phase on frag reads & stores
#define VPAD 136   // Vts rows of 128 bf16 (+8)
#define PPAD 136   // Ps rows of 128 bf16 (+8): b64 writes 2-way (free), b128 reads min-phase
#define OPAD 68    // Os rows of 64 fp32 (+4)

__device__ __forceinline__ u32 pack_bf16(float a, float b) {
  __hip_bfloat162 h = __float22bfloat162_rn(make_float2(a, b));
  u32 u; __builtin_memcpy(&u, &h, 4); return u;
}
__device__ __forceinline__ bf16x8 pack8(float4 f0, float4 f1, float sc) {
  u32 w[4];
  w[0] = pack_bf16(f0.x * sc, f0.y * sc); w[1] = pack_bf16(f0.z * sc, f0.w * sc);
  w[2] = pack_bf16(f1.x * sc, f1.y * sc); w[3] = pack_bf16(f1.z * sc, f1.w * sc);
  bf16x8 r; __builtin_memcpy(&r, w, 16); return r;
}

// ---------------- pre-pass 1: K -> (b,h,n,d) bf16 ; V -> (b,h,d,n) bf16 ----------------
__global__ void kv_convert(const float* __restrict__ k, const float* __restrict__ v,
                           u16* __restrict__ kb, u16* __restrict__ vt) {
  __shared__ u16 tile[BLK_][DK_ + 2];
  const int b = blockIdx.z, h = blockIdx.y, nb = blockIdx.x;
  const int t = threadIdx.x;
  const int rr = t >> 4, cc = (t & 15) * 4;
  // K: straight convert, (n,d) layout
  {
    const float* kg = k + ((size_t)(b * N_ + nb * BLK_)) * DM_ + h * DK_;
    u16* kd = kb + ((size_t)((b * H_ + h) * N_) + nb * BLK_) * DK_;
#pragma unroll
    for (int i = 0; i < 8; ++i) {
      const int r = rr + i * 16;
      const float4 f = *(const float4*)(kg + (size_t)r * DM_ + cc);
      *(uint2*)(kd + r * DK_ + cc) = make_uint2(pack_bf16(f.x, f.y), pack_bf16(f.z, f.w));
    }
  }
  // V: transpose via LDS, (d,n) layout
  {
    const float* vg = v + ((size_t)(b * N_ + nb * BLK_)) * DM_ + h * DK_;
#pragma unroll
    for (int i = 0; i < 8; ++i) {
      const int r = rr + i * 16;
      const float4 f = *(const float4*)(vg + (size_t)r * DM_ + cc);
      *(u32*)(&tile[r][cc])     = pack_bf16(f.x, f.y);
      *(u32*)(&tile[r][cc + 2]) = pack_bf16(f.z, f.w);
    }
    __syncthreads();
    // d = t&63: a wave reads 64 distinct d (32 distinct dword banks, pairs share a
    // dword -> broadcast) instead of d=t>>2 whose rows landed on 8 banks.
    const int d = t & 63, n0 = (t >> 6) * 32;
    u16* og = vt + ((size_t)(b * H_ + h) * DK_ + d) * N_ + nb * BLK_ + n0;
#pragma unroll
    for (int j = 0; j < 32; j += 8) {
      u16 tmp[8];
#pragma unroll
      for (int x = 0; x < 8; ++x) tmp[x] = tile[n0 + j + x][d];
      uint4 w; __builtin_memcpy(&w, tmp, 16);
      *(uint4*)(og + j) = w;
    }
  }
}

// ---------------- pre-pass 2: mask + block_sparse -> flags {0,1,2} ----------------
__global__ void mask_flags_kernel(const int* __restrict__ mask, const int* __restrict__ bs,
                                  int* __restrict__ flags) {
  const int blk = blockIdx.x;
  const int kb = blk % TB_, qb = (blk / TB_) % TB_, b = blk / (TB_ * TB_);
  const int t = threadIdx.x;
  const int* mg = mask + (size_t)b * N_ * N_ + (size_t)(qb * BLK_) * N_ + kb * BLK_;
  int all1 = 1, any1 = 0;
  for (int i = t; i < BLK_ * BLK_ / 4; i += 256) {
    const int r = i >> 5, c = (i & 31) * 4;
    const int4 mv = *(const int4*)(mg + (size_t)r * N_ + c);
    all1 &= (mv.x != 0) & (mv.y != 0) & (mv.z != 0) & (mv.w != 0);
    any1 |= (mv.x != 0) | (mv.y != 0) | (mv.z != 0) | (mv.w != 0);
  }
  __shared__ int sAll[4], sAny[4];
  const int wv = t >> 6;
  const int wAll = __all(all1), wAny = __any(any1);
  if ((t & 63) == 0) { sAll[wv] = wAll; sAny[wv] = wAny; }
  __syncthreads();
  if (t == 0) {
    const int A = sAll[0] & sAll[1] & sAll[2] & sAll[3];
    const int O = sAny[0] | sAny[1] | sAny[2] | sAny[3];
    int f = 0;
    if (bs[qb * TB_ + kb] != 0 && O) f = A ? 1 : 2;
    flags[blk] = f;
  }
}

// straight-line issue/write (no lambda; constant indices after unroll)
#define ISSUE_KV(blk_) do {                                                     \
    const u16* ks_ = kbase + (size_t)(blk_) * BLK_ * DK_;                       \
    const u16* vs_ = vbase + (blk_) * BLK_;                                     \
    _Pragma("unroll")                                                           \
    for (int j_ = 0; j_ < 4; ++j_) {                                            \
      const int i_ = t + 256 * j_;                                              \
      kr[j_] = *(const uint4*)(ks_ + i_ * 8);                                   \
      vr[j_] = *(const uint4*)(vs_ + (size_t)(i_ >> 4) * N_ + (i_ & 15) * 8);   \
    }                                                                           \
  } while (0)

#define STAGE_WRITE() do {                                                      \
    _Pragma("unroll")                                                           \
    for (int j_ = 0; j_ < 4; ++j_) {                                            \
      const int i_ = t + 256 * j_;                                              \
      *(uint4*)(Ks + (i_ >> 3) * KPAD + (i_ & 7) * 8) = kr[j_];                 \
      *(uint4*)(Vts + (i_ >> 4) * VPAD + (i_ & 15) * 8) = vr[j_];               \
    }                                                                           \
  } while (0)

// ---------------- main: block-sparse flash attention ----------------
// WG = 128 q rows. Grid 512 = (bh&31) + 32*qb -> same-(b,h) WGs share XCD.
// LDS (70656 B) caps residency at 2 WG/CU = 2 waves/SIMD. T14 issue-early /
// write-late WITHIN one iteration: block i+1's global loads are issued at the top
// of iteration i's compute and consumed by ds_write at the END of the same
// iteration (barrier, write, barrier). The compiler's mandatory vmcnt(0) drain at
// the barrier is then free -- the loads had the whole QK+softmax+PV to complete.
// kr/vr live only within one iteration body (no backedge phi, no conditional
// redefinition) -- this is what the R1/R2 loop-carried variants got wrong: 32
// loop-carried VGPRs under divergent-looking control flow went to scratch
// (+96 MB WRITE_SIZE). Sequential per-nt QK keeps live state ~150 VGPR < 256 cap.
__global__ __launch_bounds__(256, 2)
void attn_kernel(const float* __restrict__ q_, const u16* __restrict__ kb_,
                 const u16* __restrict__ vt, const float* __restrict__ tau_p,
                 const int* __restrict__ mask, const int* __restrict__ flags,
                 float* __restrict__ o_out, float* __restrict__ l_out,
                 float* __restrict__ m_out) {
  __shared__ __align__(16) u16 lds[BLK_ * KPAD + DK_ * VPAD + BLK_ * PPAD];  // 70656 B
  u16* Ks  = lds;                       // 128 x KPAD
  u16* Vts = Ks + BLK_ * KPAD;          // 64 x VPAD
  u16* Ps  = Vts + DK_ * VPAD;          // 128 x PPAD (wave-private rows)
  float* Os = (float*)lds;              // 128 x OPAD fp32 epilogue overlay (34816 <= 35840)

  const int idx = blockIdx.x;
  const int bh = idx & 31, qb128 = idx >> 5;
  const int b = bh >> 4, h = bh & 15;
  const int t = threadIdx.x;
  const int wave = t >> 6, lane = t & 63, quad = lane >> 4, col = lane & 15;

  // active-kb bitmasks (uniform across the block)
  const int* flg = flags + (b * TB_ + qb128) * TB_;
  u32 actmask = 0, mixmask = 0;
#pragma unroll
  for (int i = 0; i < TB_; ++i) {
    const int f = flg[i];
    actmask |= (f != 0) ? (1u << i) : 0u;
    mixmask |= (f == 2) ? (1u << i) : 0u;
  }

  const u16* kbase = kb_ + (size_t)(b * H_ + h) * N_ * DK_;
  const u16* vbase = vt + (size_t)(b * H_ + h) * DK_ * N_;

  uint4 kr[4], vr[4];
  u32 rem = actmask;
  int cur = -1;
  if (rem) { cur = (int)__builtin_ctz(rem); rem &= rem - 1; ISSUE_KV(cur); }  // flies under Q pack

  int qg[2];
  qg[0] = qb128 * BLK_ + wave * 32 + col;
  qg[1] = qg[0] + 16;

  // Q B-fragments straight from fp32 global (one-time; scale + log2e folded)
  const float qscale = tau_p[0] * 0.125f * 1.44269504f;
  bf16x8 bq[2][2];
#pragma unroll
  for (int nt = 0; nt < 2; ++nt) {
    const float* qr = q_ + ((size_t)(b * N_ + qg[nt])) * DM_ + h * DK_;
#pragma unroll
    for (int half = 0; half < 2; ++half) {
      const float4 f0 = *(const float4*)(qr + half * 32 + quad * 8);
      const float4 f1 = *(const float4*)(qr + half * 32 + quad * 8 + 4);
      bq[nt][half] = pack8(f0, f1, qscale);
    }
  }

  float m_run[2]  = {-INFINITY, -INFINITY};   // softmax base (may lag true max by <= THR)
  float m_true[2] = {-INFINITY, -INFINITY};   // true running max (for m_out / l_out fixup)
  float l_run[2] = {0.f, 0.f};
  f32x4 oacc[2][4];
#pragma unroll
  for (int nt = 0; nt < 2; ++nt)
#pragma unroll
    for (int mt = 0; mt < 4; ++mt) oacc[nt][mt] = (f32x4){0.f, 0.f, 0.f, 0.f};

  // prologue: stage block `cur` (loads already in flight under Q pack)
  if (cur >= 0) {
    STAGE_WRITE();
    __syncthreads();
  }

  while (cur >= 0) {
    // ---- issue next block's loads NOW; they hide under this iter's compute ----
    int nxt = -1;
    if (rem) { nxt = (int)__builtin_ctz(rem); rem &= rem - 1; ISSUE_KV(nxt); }

    const int mix = (mixmask >> cur) & 1;

    // ---- per q-tile: S^T = K.Q^T, softmax, P -> wave-private LDS ----
#pragma unroll
    for (int nt = 0; nt < 2; ++nt) {
      f32x4 st[8];
      __builtin_amdgcn_s_setprio(1);
#pragma unroll
      for (int kt = 0; kt < 8; ++kt) {
        const bf16x8 a0 = *(const bf16x8*)(Ks + (kt * 16 + col) * KPAD + quad * 8);
        const bf16x8 a1 = *(const bf16x8*)(Ks + (kt * 16 + col) * KPAD + 32 + quad * 8);
        f32x4 c = (f32x4){0.f, 0.f, 0.f, 0.f};
        c = __builtin_amdgcn_mfma_f32_16x16x32_bf16(a0, bq[nt][0], c, 0, 0, 0);
        c = __builtin_amdgcn_mfma_f32_16x16x32_bf16(a1, bq[nt][1], c, 0, 0, 0);
        st[kt] = c;
      }
      __builtin_amdgcn_s_setprio(0);
      if (mix) {  // token mask (not taken with all-ones mask)
        const int* mg = mask + (size_t)b * N_ * N_ + (size_t)qg[nt] * N_ + cur * BLK_;
#pragma unroll
        for (int kt = 0; kt < 8; ++kt) {
          const int4 mv = *(const int4*)(mg + kt * 16 + quad * 4);
          if (!mv.x) st[kt][0] = -1e30f;
          if (!mv.y) st[kt][1] = -1e30f;
          if (!mv.z) st[kt][2] = -1e30f;
          if (!mv.w) st[kt][3] = -1e30f;
        }
      }
      float mx = -INFINITY;
#pragma unroll
      for (int kt = 0; kt < 8; ++kt)
        mx = fmaxf(mx, fmaxf(fmaxf(st[kt][0], st[kt][1]), fmaxf(st[kt][2], st[kt][3])));
      mx = fmaxf(mx, __shfl_xor(mx, 16, 64));
      mx = fmaxf(mx, __shfl_xor(mx, 32, 64));
      m_true[nt] = fmaxf(m_true[nt], mx);

      // T13 defer-rescale: skip the O/l rescale unless a row grew past THR=8 (log2).
      const float mold = m_run[nt];
      float mnew = mold;
      if (!__all(mx <= mold + 8.f)) {
        mnew = fmaxf(mold, mx);
        const float alpha = __builtin_amdgcn_exp2f(mold - mnew);
        l_run[nt] *= alpha;
#pragma unroll
        for (int mt = 0; mt < 4; ++mt)
#pragma unroll
          for (int r = 0; r < 4; ++r) oacc[nt][mt][r] *= alpha;
        m_run[nt] = mnew;
      }

      const int qloc = wave * 32 + nt * 16 + col;
      float s = 0.f;
      if (!mix) {
#pragma unroll
        for (int kt = 0; kt < 8; ++kt) {
          const float p0 = __builtin_amdgcn_exp2f(st[kt][0] - mnew);
          const float p1 = __builtin_amdgcn_exp2f(st[kt][1] - mnew);
          const float p2 = __builtin_amdgcn_exp2f(st[kt][2] - mnew);
          const float p3 = __builtin_amdgcn_exp2f(st[kt][3] - mnew);
          s += (p0 + p1) + (p2 + p3);
          *(uint2*)(Ps + qloc * PPAD + kt * 16 + quad * 4) =
              make_uint2(pack_bf16(p0, p1), pack_bf16(p2, p3));
        }
      } else {
#pragma unroll
        for (int kt = 0; kt < 8; ++kt) {
          const float p0 = st[kt][0] <= -1e29f ? 0.f : __builtin_amdgcn_exp2f(st[kt][0] - mnew);
          const float p1 = st[kt][1] <= -1e29f ? 0.f : __builtin_amdgcn_exp2f(st[kt][1] - mnew);
          const float p2 = st[kt][2] <= -1e29f ? 0.f : __builtin_amdgcn_exp2f(st[kt][2] - mnew);
          const float p3 = st[kt][3] <= -1e29f ? 0.f : __builtin_amdgcn_exp2f(st[kt][3] - mnew);
          s += (p0 + p1) + (p2 + p3);
          *(uint2*)(Ps + qloc * PPAD + kt * 16 + quad * 4) =
              make_uint2(pack_bf16(p0, p1), pack_bf16(p2, p3));
        }
      }
      s += __shfl_xor(s, 16, 64);
      s += __shfl_xor(s, 32, 64);
      l_run[nt] += s;
    }

    // ---- O^T += V^T . P^T ; P fragments from wave-private LDS (no barrier) ----
    __builtin_amdgcn_s_setprio(1);
#pragma unroll
    for (int ks = 0; ks < 4; ++ks) {
      bf16x8 bfrag[2];
#pragma unroll
      for (int nt = 0; nt < 2; ++nt)
        bfrag[nt] = *(const bf16x8*)(Ps + (wave * 32 + nt * 16 + col) * PPAD + ks * 32 + quad * 8);
#pragma unroll
      for (int mt = 0; mt < 4; ++mt) {
        const bf16x8 av = *(const bf16x8*)(Vts + (mt * 16 + col) * VPAD + ks * 32 + quad * 8);
#pragma unroll
        for (int nt = 0; nt < 2; ++nt)
          oacc[nt][mt] = __builtin_amdgcn_mfma_f32_16x16x32_bf16(av, bfrag[nt], oacc[nt][mt], 0, 0, 0);
      }
    }
    __builtin_amdgcn_s_setprio(0);

    // ---- write-late: stage block `nxt` (loads completed during compute) ----
    if (nxt >= 0) {
      __syncthreads();   // all waves done reading Ks/Vts of `cur`
      STAGE_WRITE();     // vmcnt drain here is free; values ready
      __syncthreads();   // staging visible for next iteration
    }
    cur = nxt;
  }

  // ---- epilogue: normalize, transpose O through LDS overlay, coalesced writes ----
  __syncthreads();  // all waves done with Ks/Vts before Os overlay
#pragma unroll
  for (int nt = 0; nt < 2; ++nt) {
    const float inv = l_run[nt] > 0.f ? 1.f / l_run[nt] : 1.f;
    const int qloc = wave * 32 + nt * 16 + col;
#pragma unroll
    for (int mt = 0; mt < 4; ++mt) {
      float4 w = make_float4(oacc[nt][mt][0] * inv, oacc[nt][mt][1] * inv,
                             oacc[nt][mt][2] * inv, oacc[nt][mt][3] * inv);
      *(float4*)(Os + qloc * OPAD + mt * 16 + quad * 4) = w;
    }
  }
  __syncthreads();
  float* ob = o_out + ((size_t)(b * N_ + qb128 * BLK_)) * DM_ + h * DK_;
#pragma unroll
  for (int j = 0; j < 8; ++j) {
    const int i = t + 256 * j;
    const int r = i >> 4, c4 = (i & 15) * 4;
    const float4 w = *(const float4*)(Os + r * OPAD + c4);
    *(float4*)(ob + (size_t)r * DM_ + c4) = w;
  }
  if (quad == 0) {
#pragma unroll
    for (int nt = 0; nt < 2; ++nt) {
      const size_t oi = (size_t)(b * H_ + h) * N_ + qg[nt];
      // l_run is consistent with base m_run; convert to the true-max base.
      const float lv = l_run[nt] > 0.f
          ? l_run[nt] * __builtin_amdgcn_exp2f(m_run[nt] - m_true[nt]) : 0.f;
      l_out[oi] = lv;
      m_out[oi] = l_run[nt] > 0.f ? m_true[nt] * 0.69314718056f : -INFINITY;
    }
  }
}

extern "C" void kernel_launch(void* const* d_in, const int* in_sizes, int n_in,
                              void* d_out, int out_size, void* d_ws, size_t ws_size,
                              hipStream_t stream) {
  const float* q   = (const float*)d_in[0];
  const float* k   = (const float*)d_in[1];
  const float* v   = (const float*)d_in[2];
  const float* tau = (const float*)d_in[3];
  const int* mask  = (const int*)d_in[4];
  const int* bs    = (const int*)d_in[5];
  float* out = (float*)d_out;

  const size_t plane = (size_t)B_ * H_ * N_ * DK_;
  u16* kb = (u16*)d_ws;
  u16* vt = kb + plane;
  int* flags = (int*)(vt + plane);

  kv_convert<<<dim3(N_ / BLK_, H_, B_), 256, 0, stream>>>(k, v, kb, vt);
  mask_flags_kernel<<<B_ * TB_ * TB_, 256, 0, stream>>>(mask, bs, flags);

  float* o_out = out;
  float* l_out = out + (size_t)B_ * N_ * DM_;
  float* m_out = l_out + (size_t)B_ * H_ * N_;
  attn_kernel<<<dim3(TB_ * 32), 256, 0, stream>>>(q, kb, vt, tau, mask, flags,
                                                  o_out, l_out, m_out);
}

// Round 4
// 165.674 us; speedup vs baseline: 1.1673x; 1.1596x over previous
//
#include <hip/hip_runtime.h>
#include <hip/hip_bf16.h>

#define B_   2
#define N_   2048
#define DM_  1024
#define H_   16
#define DK_  64
#define BLK_ 128
#define TB_  16

typedef unsigned short u16;
typedef unsigned int   u32;
using bf16x8 = __attribute__((ext_vector_type(8))) __bf16;
using f32x4  = __attribute__((ext_vector_type(4))) float;

#define KPAD 72    // Ks rows of 64 bf16 (+8): min-phase on frag reads & stores
#define VPAD 136   // Vts rows of 128 bf16 (+8)
#define PPAD 136   // Ps rows of 128 bf16 (+8): b64 writes 2-way (free), b128 reads min-phase
#define OPAD 68    // Os rows of 64 fp32 (+4)

__device__ __forceinline__ u32 pack_bf16(float a, float b) {
  __hip_bfloat162 h = __float22bfloat162_rn(make_float2(a, b));
  u32 u; __builtin_memcpy(&u, &h, 4); return u;
}
__device__ __forceinline__ bf16x8 pack8(float4 f0, float4 f1, float sc) {
  u32 w[4];
  w[0] = pack_bf16(f0.x * sc, f0.y * sc); w[1] = pack_bf16(f0.z * sc, f0.w * sc);
  w[2] = pack_bf16(f1.x * sc, f1.y * sc); w[3] = pack_bf16(f1.z * sc, f1.w * sc);
  bf16x8 r; __builtin_memcpy(&r, w, 16); return r;
}

// ---------------- pre-pass 1: K -> (b,h,n,d) bf16 ; V -> (b,h,d,n) bf16 ----------------
__global__ void kv_convert(const float* __restrict__ k, const float* __restrict__ v,
                           u16* __restrict__ kb, u16* __restrict__ vt) {
  __shared__ u16 tile[BLK_][DK_ + 2];
  const int b = blockIdx.z, h = blockIdx.y, nb = blockIdx.x;
  const int t = threadIdx.x;
  const int rr = t >> 4, cc = (t & 15) * 4;
  // K: straight convert, (n,d) layout
  {
    const float* kg = k + ((size_t)(b * N_ + nb * BLK_)) * DM_ + h * DK_;
    u16* kd = kb + ((size_t)((b * H_ + h) * N_) + nb * BLK_) * DK_;
#pragma unroll
    for (int i = 0; i < 8; ++i) {
      const int r = rr + i * 16;
      const float4 f = *(const float4*)(kg + (size_t)r * DM_ + cc);
      *(uint2*)(kd + r * DK_ + cc) = make_uint2(pack_bf16(f.x, f.y), pack_bf16(f.z, f.w));
    }
  }
  // V: transpose via LDS, (d,n) layout
  {
    const float* vg = v + ((size_t)(b * N_ + nb * BLK_)) * DM_ + h * DK_;
#pragma unroll
    for (int i = 0; i < 8; ++i) {
      const int r = rr + i * 16;
      const float4 f = *(const float4*)(vg + (size_t)r * DM_ + cc);
      *(u32*)(&tile[r][cc])     = pack_bf16(f.x, f.y);
      *(u32*)(&tile[r][cc + 2]) = pack_bf16(f.z, f.w);
    }
    __syncthreads();
    // d = t&63: a wave reads 64 distinct d (32 distinct dword banks, adjacent pairs
    // share a dword -> broadcast) instead of d=t>>2 whose rows landed on 8 banks.
    const int d = t & 63, n0 = (t >> 6) * 32;
    u16* og = vt + ((size_t)(b * H_ + h) * DK_ + d) * N_ + nb * BLK_ + n0;
#pragma unroll
    for (int j = 0; j < 32; j += 8) {
      u16 tmp[8];
#pragma unroll
      for (int x = 0; x < 8; ++x) tmp[x] = tile[n0 + j + x][d];
      uint4 w; __builtin_memcpy(&w, tmp, 16);
      *(uint4*)(og + j) = w;
    }
  }
}

// ---------------- pre-pass 2: mask + block_sparse -> flags {0,1,2} ----------------
__global__ void mask_flags_kernel(const int* __restrict__ mask, const int* __restrict__ bs,
                                  int* __restrict__ flags) {
  const int blk = blockIdx.x;
  const int kb = blk % TB_, qb = (blk / TB_) % TB_, b = blk / (TB_ * TB_);
  const int t = threadIdx.x;
  const int* mg = mask + (size_t)b * N_ * N_ + (size_t)(qb * BLK_) * N_ + kb * BLK_;
  int all1 = 1, any1 = 0;
  for (int i = t; i < BLK_ * BLK_ / 4; i += 256) {
    const int r = i >> 5, c = (i & 31) * 4;
    const int4 mv = *(const int4*)(mg + (size_t)r * N_ + c);
    all1 &= (mv.x != 0) & (mv.y != 0) & (mv.z != 0) & (mv.w != 0);
    any1 |= (mv.x != 0) | (mv.y != 0) | (mv.z != 0) | (mv.w != 0);
  }
  __shared__ int sAll[4], sAny[4];
  const int wv = t >> 6;
  const int wAll = __all(all1), wAny = __any(any1);
  if ((t & 63) == 0) { sAll[wv] = wAll; sAny[wv] = wAny; }
  __syncthreads();
  if (t == 0) {
    const int A = sAll[0] & sAll[1] & sAll[2] & sAll[3];
    const int O = sAny[0] | sAny[1] | sAny[2] | sAny[3];
    int f = 0;
    if (bs[qb * TB_ + kb] != 0 && O) f = A ? 1 : 2;
    flags[blk] = f;
  }
}

// ---------------- main: block-sparse flash attention ----------------
// WG = 128 q rows. Grid 512 = (bh&31) + 32*qb -> same-(b,h) WGs share XCD (K/V L2
// reuse; FETCH ~ideal). q = col lane in both MFMA C-layouts -> per-lane softmax.
// P round-trips through WAVE-PRIVATE LDS rows (no barrier). Staging is the plain
// load->ds_write between two barriers: the loads are L2-hits (~200cy) since 16
// qb-WGs share each (b,h) K/V plane -- register prefetch is NOT worth it, and all
// three prefetch variants (R1-R3) put kr/vr in scratch (+94 MB WRITE_SIZE, the
// compiler won't promote conditionally-written arrays). Keep VGPR ~100, no spill.
// Session adds vs original baseline: T5 setprio around MFMA clusters, T13
// defer-rescale (THR=8 log2, m_true tracked for l/m outputs).
__global__ __launch_bounds__(256, 2)
void attn_kernel(const float* __restrict__ q_, const u16* __restrict__ kb_,
                 const u16* __restrict__ vt, const float* __restrict__ tau_p,
                 const int* __restrict__ mask, const int* __restrict__ flags,
                 float* __restrict__ o_out, float* __restrict__ l_out,
                 float* __restrict__ m_out) {
  __shared__ __align__(16) u16 lds[BLK_ * KPAD + DK_ * VPAD + BLK_ * PPAD];  // 70656 B
  u16* Ks  = lds;                       // 128 x KPAD
  u16* Vts = Ks + BLK_ * KPAD;          // 64 x VPAD
  u16* Ps  = Vts + DK_ * VPAD;          // 128 x PPAD (wave-private rows)
  float* Os = (float*)lds;              // 128 x OPAD fp32 epilogue overlay (34816 <= 35840)

  const int idx = blockIdx.x;
  const int bh = idx & 31, qb128 = idx >> 5;
  const int b = bh >> 4, h = bh & 15;
  const int t = threadIdx.x;
  const int wave = t >> 6, lane = t & 63, quad = lane >> 4, col = lane & 15;

  // active-kb bitmasks (uniform)
  const int* flg = flags + (b * TB_ + qb128) * TB_;
  u32 actmask = 0, mixmask = 0;
#pragma unroll
  for (int i = 0; i < TB_; ++i) {
    const int f = flg[i];
    actmask |= (f != 0) ? (1u << i) : 0u;
    mixmask |= (f == 2) ? (1u << i) : 0u;
  }

  int qg[2];
  qg[0] = qb128 * BLK_ + wave * 32 + col;
  qg[1] = qg[0] + 16;

  // Q B-fragments straight from fp32 global (one-time; scale + log2e folded)
  const float qscale = tau_p[0] * 0.125f * 1.44269504f;
  bf16x8 bq[2][2];
#pragma unroll
  for (int nt = 0; nt < 2; ++nt) {
    const float* qr = q_ + ((size_t)(b * N_ + qg[nt])) * DM_ + h * DK_;
#pragma unroll
    for (int half = 0; half < 2; ++half) {
      const float4 f0 = *(const float4*)(qr + half * 32 + quad * 8);
      const float4 f1 = *(const float4*)(qr + half * 32 + quad * 8 + 4);
      bq[nt][half] = pack8(f0, f1, qscale);
    }
  }

  float m_run[2]  = {-INFINITY, -INFINITY};   // softmax base (may lag true max by <= THR)
  float m_true[2] = {-INFINITY, -INFINITY};   // true running max (for m_out / l_out fixup)
  float l_run[2] = {0.f, 0.f};
  f32x4 oacc[2][4];
#pragma unroll
  for (int nt = 0; nt < 2; ++nt)
#pragma unroll
    for (int mt = 0; mt < 4; ++mt) oacc[nt][mt] = (f32x4){0.f, 0.f, 0.f, 0.f};

  const u16* kbase = kb_ + (size_t)(b * H_ + h) * N_ * DK_;
  const u16* vbase = vt + (size_t)(b * H_ + h) * DK_ * N_;

  u32 rem = actmask;
  while (rem) {
    const int cur = (int)__builtin_ctz(rem);
    rem &= rem - 1;
    const int mix = (mixmask >> cur) & 1;

    __syncthreads();  // previous iter's K/V fragment reads complete
    // ---- stage K,V (L2-resident after first qb touches them) ----
    {
      const u16* ks = kbase + (size_t)cur * BLK_ * DK_;
      const u16* vs = vbase + cur * BLK_;
      uint4 kr[4], vr[4];
#pragma unroll
      for (int j = 0; j < 4; ++j) {
        const int i = t + 256 * j;
        kr[j] = *(const uint4*)(ks + i * 8);
        vr[j] = *(const uint4*)(vs + (size_t)(i >> 4) * N_ + (i & 15) * 8);
      }
#pragma unroll
      for (int j = 0; j < 4; ++j) {
        const int i = t + 256 * j;
        *(uint4*)(Ks + (i >> 3) * KPAD + (i & 7) * 8) = kr[j];
        *(uint4*)(Vts + (i >> 4) * VPAD + (i & 15) * 8) = vr[j];
      }
    }
    __syncthreads();

    // ---- per q-tile: S^T = K.Q^T, softmax, P -> wave-private LDS ----
#pragma unroll
    for (int nt = 0; nt < 2; ++nt) {
      f32x4 st[8];
      __builtin_amdgcn_s_setprio(1);
#pragma unroll
      for (int kt = 0; kt < 8; ++kt) {
        const bf16x8 a0 = *(const bf16x8*)(Ks + (kt * 16 + col) * KPAD + quad * 8);
        const bf16x8 a1 = *(const bf16x8*)(Ks + (kt * 16 + col) * KPAD + 32 + quad * 8);
        f32x4 c = (f32x4){0.f, 0.f, 0.f, 0.f};
        c = __builtin_amdgcn_mfma_f32_16x16x32_bf16(a0, bq[nt][0], c, 0, 0, 0);
        c = __builtin_amdgcn_mfma_f32_16x16x32_bf16(a1, bq[nt][1], c, 0, 0, 0);
        st[kt] = c;
      }
      __builtin_amdgcn_s_setprio(0);
      if (mix) {  // token mask (not taken with all-ones mask)
        const int* mg = mask + (size_t)b * N_ * N_ + (size_t)qg[nt] * N_ + cur * BLK_;
#pragma unroll
        for (int kt = 0; kt < 8; ++kt) {
          const int4 mv = *(const int4*)(mg + kt * 16 + quad * 4);
          if (!mv.x) st[kt][0] = -1e30f;
          if (!mv.y) st[kt][1] = -1e30f;
          if (!mv.z) st[kt][2] = -1e30f;
          if (!mv.w) st[kt][3] = -1e30f;
        }
      }
      float mx = -INFINITY;
#pragma unroll
      for (int kt = 0; kt < 8; ++kt)
        mx = fmaxf(mx, fmaxf(fmaxf(st[kt][0], st[kt][1]), fmaxf(st[kt][2], st[kt][3])));
      mx = fmaxf(mx, __shfl_xor(mx, 16, 64));
      mx = fmaxf(mx, __shfl_xor(mx, 32, 64));
      m_true[nt] = fmaxf(m_true[nt], mx);

      // T13 defer-rescale: skip the O/l rescale unless a row grew past THR=8 (log2).
      const float mold = m_run[nt];
      float mnew = mold;
      if (!__all(mx <= mold + 8.f)) {
        mnew = fmaxf(mold, mx);
        const float alpha = __builtin_amdgcn_exp2f(mold - mnew);
        l_run[nt] *= alpha;
#pragma unroll
        for (int mt = 0; mt < 4; ++mt)
#pragma unroll
          for (int r = 0; r < 4; ++r) oacc[nt][mt][r] *= alpha;
        m_run[nt] = mnew;
      }

      const int qloc = wave * 32 + nt * 16 + col;
      float s = 0.f;
      if (!mix) {
#pragma unroll
        for (int kt = 0; kt < 8; ++kt) {
          const float p0 = __builtin_amdgcn_exp2f(st[kt][0] - mnew);
          const float p1 = __builtin_amdgcn_exp2f(st[kt][1] - mnew);
          const float p2 = __builtin_amdgcn_exp2f(st[kt][2] - mnew);
          const float p3 = __builtin_amdgcn_exp2f(st[kt][3] - mnew);
          s += (p0 + p1) + (p2 + p3);
          *(uint2*)(Ps + qloc * PPAD + kt * 16 + quad * 4) =
              make_uint2(pack_bf16(p0, p1), pack_bf16(p2, p3));
        }
      } else {
#pragma unroll
        for (int kt = 0; kt < 8; ++kt) {
          const float p0 = st[kt][0] <= -1e29f ? 0.f : __builtin_amdgcn_exp2f(st[kt][0] - mnew);
          const float p1 = st[kt][1] <= -1e29f ? 0.f : __builtin_amdgcn_exp2f(st[kt][1] - mnew);
          const float p2 = st[kt][2] <= -1e29f ? 0.f : __builtin_amdgcn_exp2f(st[kt][2] - mnew);
          const float p3 = st[kt][3] <= -1e29f ? 0.f : __builtin_amdgcn_exp2f(st[kt][3] - mnew);
          s += (p0 + p1) + (p2 + p3);
          *(uint2*)(Ps + qloc * PPAD + kt * 16 + quad * 4) =
              make_uint2(pack_bf16(p0, p1), pack_bf16(p2, p3));
        }
      }
      s += __shfl_xor(s, 16, 64);
      s += __shfl_xor(s, 32, 64);
      l_run[nt] += s;
    }

    // ---- O^T += V^T . P^T ; P fragments from wave-private LDS (no barrier) ----
    __builtin_amdgcn_s_setprio(1);
#pragma unroll
    for (int ks = 0; ks < 4; ++ks) {
      bf16x8 bfrag[2];
#pragma unroll
      for (int nt = 0; nt < 2; ++nt)
        bfrag[nt] = *(const bf16x8*)(Ps + (wave * 32 + nt * 16 + col) * PPAD + ks * 32 + quad * 8);
#pragma unroll
      for (int mt = 0; mt < 4; ++mt) {
        const bf16x8 av = *(const bf16x8*)(Vts + (mt * 16 + col) * VPAD + ks * 32 + quad * 8);
#pragma unroll
        for (int nt = 0; nt < 2; ++nt)
          oacc[nt][mt] = __builtin_amdgcn_mfma_f32_16x16x32_bf16(av, bfrag[nt], oacc[nt][mt], 0, 0, 0);
      }
    }
    __builtin_amdgcn_s_setprio(0);
  }

  // ---- epilogue: normalize, transpose O through LDS overlay, coalesced writes ----
  __syncthreads();  // all waves done with Ks/Vts before Os overlay
#pragma unroll
  for (int nt = 0; nt < 2; ++nt) {
    const float inv = l_run[nt] > 0.f ? 1.f / l_run[nt] : 1.f;
    const int qloc = wave * 32 + nt * 16 + col;
#pragma unroll
    for (int mt = 0; mt < 4; ++mt) {
      float4 w = make_float4(oacc[nt][mt][0] * inv, oacc[nt][mt][1] * inv,
                             oacc[nt][mt][2] * inv, oacc[nt][mt][3] * inv);
      *(float4*)(Os + qloc * OPAD + mt * 16 + quad * 4) = w;
    }
  }
  __syncthreads();
  float* ob = o_out + ((size_t)(b * N_ + qb128 * BLK_)) * DM_ + h * DK_;
#pragma unroll
  for (int j = 0; j < 8; ++j) {
    const int i = t + 256 * j;
    const int r = i >> 4, c4 = (i & 15) * 4;
    const float4 w = *(const float4*)(Os + r * OPAD + c4);
    *(float4*)(ob + (size_t)r * DM_ + c4) = w;
  }
  if (quad == 0) {
#pragma unroll
    for (int nt = 0; nt < 2; ++nt) {
      const size_t oi = (size_t)(b * H_ + h) * N_ + qg[nt];
      // l_run is consistent with base m_run; convert to the true-max base.
      const float lv = l_run[nt] > 0.f
          ? l_run[nt] * __builtin_amdgcn_exp2f(m_run[nt] - m_true[nt]) : 0.f;
      l_out[oi] = lv;
      m_out[oi] = l_run[nt] > 0.f ? m_true[nt] * 0.69314718056f : -INFINITY;
    }
  }
}

extern "C" void kernel_launch(void* const* d_in, const int* in_sizes, int n_in,
                              void* d_out, int out_size, void* d_ws, size_t ws_size,
                              hipStream_t stream) {
  const float* q   = (const float*)d_in[0];
  const float* k   = (const float*)d_in[1];
  const float* v   = (const float*)d_in[2];
  const float* tau = (const float*)d_in[3];
  const int* mask  = (const int*)d_in[4];
  const int* bs    = (const int*)d_in[5];
  float* out = (float*)d_out;

  const size_t plane = (size_t)B_ * H_ * N_ * DK_;
  u16* kb = (u16*)d_ws;
  u16* vt = kb + plane;
  int* flags = (int*)(vt + plane);

  kv_convert<<<dim3(N_ / BLK_, H_, B_), 256, 0, stream>>>(k, v, kb, vt);
  mask_flags_kernel<<<B_ * TB_ * TB_, 256, 0, stream>>>(mask, bs, flags);

  float* o_out = out;
  float* l_out = out + (size_t)B_ * N_ * DM_;
  float* m_out = l_out + (size_t)B_ * H_ * N_;
  attn_kernel<<<dim3(TB_ * 32), 256, 0, stream>>>(q, kb, vt, tau, mask, flags,
                                                  o_out, l_out, m_out);
}